// Round 3
// baseline (277.327 us; speedup 1.0000x reference)
//
#include <hip/hip_runtime.h>
#include <math.h>

// KLDiracVMF: losses/l1/l2/l3 for vMF KL with Dirac, d=512, r=64, v=255.
// R3: latency-bound fix. 16 lanes/row, 4 rows/wave:
//   - 16x float4 loads per lane (16 KB in flight per wave, was 4 KB)
//   - butterflies are 4 steps over 16 lanes serving 4 rows (12 dependent
//     DS ops per wave, was 72 per 4 rows)
//   - series window 128 terms (edge >=10 nats below peak; error << bf16 ulp)
// lg[k]=lgamma(k+1)+lgamma(k+256) precomputed via prefix-scan (d_ws).

#define K_TERMS 700
#define WND 128            // series window; 8 terms per lane (16-lane groups)
#define ZD 512
#define VV 255.0f
// 256*log(2*pi) + 512*log(64)
#define CONST_TERM 2599.8446676805443f

__global__ __launch_bounds__(256) void lg_table_kernel(float* __restrict__ lg) {
    __shared__ double ssum[256];
    const int t = threadIdx.x;
    // lg[k] = lgamma(256) + sum_{j=1..k} (log j + log(j+255)); 3 entries/thread
    double loc[3];
    double tot = 0.0;
    #pragma unroll
    for (int i = 0; i < 3; ++i) {
        int p = t * 3 + i;                    // 0..767
        double inc = 0.0;
        if (p >= 1 && p < K_TERMS)
            inc = log((double)p) + log((double)(p + 255));
        tot += inc;
        loc[i] = tot;                         // inclusive prefix within thread
    }
    ssum[t] = tot;
    __syncthreads();
    for (int off = 1; off < 256; off <<= 1) {
        double v = (t >= off) ? ssum[t - off] : 0.0;
        __syncthreads();
        ssum[t] += v;
        __syncthreads();
    }
    const double excl = (t == 0) ? 0.0 : ssum[t - 1];
    const double z = 256.0;
    const double base = (z - 0.5) * log(z) - z + 0.918938533204672741780
                      + 1.0 / (12.0 * z) - 1.0 / (360.0 * z * z * z);
    #pragma unroll
    for (int i = 0; i < 3; ++i) {
        int p = t * 3 + i;
        if (p < K_TERMS) lg[p] = (float)(base + excl + loc[i]);
    }
}

__global__ __launch_bounds__(256) void vmf_kernel(
    const float* __restrict__ mu, const float* __restrict__ kappa,
    const float* __restrict__ wc, const float* __restrict__ lg,
    float* __restrict__ out, int B)
{
    const int tid  = (int)threadIdx.x;
    const int wv   = tid >> 6;                 // wave in block (0..3)
    const int lane = tid & 63;
    const int grp  = lane >> 4;                // row-slot within wave (0..3)
    const int sub  = lane & 15;                // lane within row group
    const int row  = ((int)blockIdx.x * 4 + wv) * 4 + grp;
    if (row >= B) return;

    const float kap = kappa[row];

    // ---- dot(mu_row, wc_row): 16 lanes/row, 8 float4 per lane per operand ----
    const float4* m4 = (const float4*)(mu + (size_t)row * ZD);
    const float4* w4 = (const float4*)(wc + (size_t)row * ZD);
    float dp = 0.0f;
    #pragma unroll
    for (int j = 0; j < 8; ++j) {
        float4 a = m4[sub + 16 * j];
        float4 b = w4[sub + 16 * j];
        dp += a.x * b.x + a.y * b.y + a.z * b.z + a.w * b.w;
    }

    const float L = logf(0.5f * kap);          // log(x/2)

    // ---- 128-term window centered at the series peak ----
    const float kstar = 0.5f * (sqrtf(65025.0f + kap * kap) - 255.0f);
    int klo = (int)kstar - (WND / 2);
    klo = klo < 0 ? 0 : (klo > (K_TERMS - WND) ? (K_TERMS - WND) : klo);

    // ---- two-pass logsumexp over group of 16 lanes, 8 terms/lane ----
    float t[8];
    #pragma unroll
    for (int j = 0; j < 8; ++j) {
        int k = klo + sub + 16 * j;
        t[j] = fmaf((float)(2 * k), L, -lg[k]);
    }
    float m = t[0];
    #pragma unroll
    for (int j = 1; j < 8; ++j) m = fmaxf(m, t[j]);
    #pragma unroll
    for (int off = 8; off >= 1; off >>= 1)
        m = fmaxf(m, __shfl_xor(m, off, 64));  // xor<16 stays within group
    float s = 0.0f;
    #pragma unroll
    for (int j = 0; j < 8; ++j) s += __expf(t[j] - m);
    #pragma unroll
    for (int off = 8; off >= 1; off >>= 1)
        s += __shfl_xor(s, off, 64);

    // ---- dp reduction across the 16-lane group ----
    #pragma unroll
    for (int off = 8; off >= 1; off >>= 1)
        dp += __shfl_xor(dp, off, 64);

    const float lse = m + logf(s);

    // ---- assemble outputs ----
    const float log_ive      = VV * L + lse - kap;          // log(I_v(k)e^-k)
    const float log_ive_kap  = logf(1e-6f + __expf(log_ive));
    const float log_iv_kappa = log_ive_kap + kap;
    const float cos_theta    = dp * (1.0f / 64.0f);

    const float l1 = -kap * cos_theta;
    const float l2 = -VV * logf(1e-6f + kap);
    const float l3 = log_iv_kappa;
    const float losses = l1 + l2 + l3 + CONST_TERM;

    if (sub == 0) {
        out[row]                 = losses;
        out[(size_t)B + row]     = l1;
        out[(size_t)2 * B + row] = l2;
        out[(size_t)3 * B + row] = l3;
    }
}

extern "C" void kernel_launch(void* const* d_in, const int* in_sizes, int n_in,
                              void* d_out, int out_size, void* d_ws, size_t ws_size,
                              hipStream_t stream) {
    const float* mu    = (const float*)d_in[0];
    const float* kappa = (const float*)d_in[1];
    const float* wc    = (const float*)d_in[2];
    float* out = (float*)d_out;
    float* lg  = (float*)d_ws;   // K_TERMS floats of scratch
    const int B = in_sizes[1];   // kappa is [B,1]

    lg_table_kernel<<<1, 256, 0, stream>>>(lg);
    // 16 rows per 256-thread block (4 waves x 4 rows)
    vmf_kernel<<<(B + 15) / 16, 256, 0, stream>>>(mu, kappa, wc, lg, out, B);
}

// Round 5
// 255.912 us; speedup vs baseline: 1.0837x; 1.0837x over previous
//
#include <hip/hip_runtime.h>
#include <math.h>

// KLDiracVMF: losses/l1/l2/l3 for vMF KL with Dirac, d=512, r=64, v=255.
// R5 = R4 with the nontemporal-load type fixed (native clang ext_vector_type
// instead of HIP_vector_type; builtin requires scalar/native-vector pointee).
// Design: persistent grid (2048 blocks), 2 row-batches per wave, register
// double-buffer (next batch's 16 float4 nt-loads issued before reducing the
// current batch), 4 rows/wave x 16 lanes/row.

#define K_TERMS 700
#define WND 128            // series window; 8 terms per lane (16-lane groups)
#define ZD 512
#define VV 255.0f
// 256*log(2*pi) + 512*log(64)
#define CONST_TERM 2599.8446676805443f
#define NBLOCKS 2048

typedef float f4 __attribute__((ext_vector_type(4)));

__global__ __launch_bounds__(256) void lg_table_kernel(float* __restrict__ lg) {
    __shared__ double ssum[256];
    const int t = threadIdx.x;
    // lg[k] = lgamma(256) + sum_{j=1..k} (log j + log(j+255)); 3 entries/thread
    double loc[3];
    double tot = 0.0;
    #pragma unroll
    for (int i = 0; i < 3; ++i) {
        int p = t * 3 + i;                    // 0..767
        double inc = 0.0;
        if (p >= 1 && p < K_TERMS)
            inc = log((double)p) + log((double)(p + 255));
        tot += inc;
        loc[i] = tot;                         // inclusive prefix within thread
    }
    ssum[t] = tot;
    __syncthreads();
    for (int off = 1; off < 256; off <<= 1) {
        double v = (t >= off) ? ssum[t - off] : 0.0;
        __syncthreads();
        ssum[t] += v;
        __syncthreads();
    }
    const double excl = (t == 0) ? 0.0 : ssum[t - 1];
    const double z = 256.0;
    const double base = (z - 0.5) * log(z) - z + 0.918938533204672741780
                      + 1.0 / (12.0 * z) - 1.0 / (360.0 * z * z * z);
    #pragma unroll
    for (int i = 0; i < 3; ++i) {
        int p = t * 3 + i;
        if (p < K_TERMS) lg[p] = (float)(base + excl + loc[i]);
    }
}

__global__ __launch_bounds__(256) void vmf_kernel(
    const float* __restrict__ mu, const float* __restrict__ kappa,
    const float* __restrict__ wc, const float* __restrict__ lg,
    float* __restrict__ out, int B)
{
    const int tid  = (int)threadIdx.x;
    const int wv   = tid >> 6;
    const int lane = tid & 63;
    const int grp  = lane >> 4;                // row-slot within wave (0..3)
    const int sub  = lane & 15;                // lane within row group
    const int nwaves  = (int)gridDim.x << 2;
    const int ngroups = (B + 3) >> 2;          // groups of 4 rows

    int g = (int)blockIdx.x * 4 + wv;
    if (g >= ngroups) return;

    f4 a[8], b[8];
    {   // preamble: load batch for first g
        int row = g * 4 + grp; if (row >= B) row = B - 1;
        const f4* m4 = (const f4*)(mu + (size_t)row * ZD);
        const f4* w4 = (const f4*)(wc + (size_t)row * ZD);
        #pragma unroll
        for (int j = 0; j < 8; ++j) {
            a[j] = __builtin_nontemporal_load(&m4[sub + 16 * j]);
            b[j] = __builtin_nontemporal_load(&w4[sub + 16 * j]);
        }
    }

    while (g < ngroups) {
        const int gn = g + nwaves;
        // ---- issue next batch's loads before consuming current ----
        f4 an[8], bn[8];
        if (gn < ngroups) {
            int rown = gn * 4 + grp; if (rown >= B) rown = B - 1;
            const f4* m4 = (const f4*)(mu + (size_t)rown * ZD);
            const f4* w4 = (const f4*)(wc + (size_t)rown * ZD);
            #pragma unroll
            for (int j = 0; j < 8; ++j) {
                an[j] = __builtin_nontemporal_load(&m4[sub + 16 * j]);
                bn[j] = __builtin_nontemporal_load(&w4[sub + 16 * j]);
            }
        }

        // ---- consume current batch ----
        int row = g * 4 + grp;
        const bool valid = row < B; if (!valid) row = B - 1;
        const float kap = kappa[row];

        float dp = 0.0f;
        #pragma unroll
        for (int j = 0; j < 8; ++j)
            dp += a[j].x * b[j].x + a[j].y * b[j].y
                + a[j].z * b[j].z + a[j].w * b[j].w;

        const float L = logf(0.5f * kap);      // log(x/2)
        const float kstar = 0.5f * (sqrtf(65025.0f + kap * kap) - 255.0f);
        int klo = (int)kstar - (WND / 2);
        klo = klo < 0 ? 0 : (klo > (K_TERMS - WND) ? (K_TERMS - WND) : klo);

        float t[8];
        #pragma unroll
        for (int j = 0; j < 8; ++j) {
            int k = klo + sub + 16 * j;
            t[j] = fmaf((float)(2 * k), L, -lg[k]);
        }
        float m = t[0];
        #pragma unroll
        for (int j = 1; j < 8; ++j) m = fmaxf(m, t[j]);
        #pragma unroll
        for (int off = 8; off >= 1; off >>= 1)
            m = fmaxf(m, __shfl_xor(m, off, 64));   // xor<16 stays in group
        float s = 0.0f;
        #pragma unroll
        for (int j = 0; j < 8; ++j) s += __expf(t[j] - m);
        #pragma unroll
        for (int off = 8; off >= 1; off >>= 1)
            s += __shfl_xor(s, off, 64);
        #pragma unroll
        for (int off = 8; off >= 1; off >>= 1)
            dp += __shfl_xor(dp, off, 64);

        const float lse = m + logf(s);
        const float log_ive      = VV * L + lse - kap;
        const float log_ive_kap  = logf(1e-6f + __expf(log_ive));
        const float log_iv_kappa = log_ive_kap + kap;
        const float cos_theta    = dp * (1.0f / 64.0f);

        const float l1 = -kap * cos_theta;
        const float l2 = -VV * logf(1e-6f + kap);
        const float l3 = log_iv_kappa;
        const float losses = l1 + l2 + l3 + CONST_TERM;

        if (sub == 0 && valid) {
            out[row]                 = losses;
            out[(size_t)B + row]     = l1;
            out[(size_t)2 * B + row] = l2;
            out[(size_t)3 * B + row] = l3;
        }

        // ---- rotate buffers ----
        #pragma unroll
        for (int j = 0; j < 8; ++j) { a[j] = an[j]; b[j] = bn[j]; }
        g = gn;
    }
}

extern "C" void kernel_launch(void* const* d_in, const int* in_sizes, int n_in,
                              void* d_out, int out_size, void* d_ws, size_t ws_size,
                              hipStream_t stream) {
    const float* mu    = (const float*)d_in[0];
    const float* kappa = (const float*)d_in[1];
    const float* wc    = (const float*)d_in[2];
    float* out = (float*)d_out;
    float* lg  = (float*)d_ws;   // K_TERMS floats of scratch
    const int B = in_sizes[1];   // kappa is [B,1]

    lg_table_kernel<<<1, 256, 0, stream>>>(lg);
    // persistent-ish grid: 2048 blocks x 4 waves; each wave does 2 row-batches
    vmf_kernel<<<NBLOCKS, 256, 0, stream>>>(mu, kappa, wc, lg, out, B);
}